// Round 1
// baseline (48.923 us; speedup 1.0000x reference)
//
#include <hip/hip_runtime.h>

// x: [64, 3, 512, 512] f32 in [0,1). Per (b,c) slice: 128-bin histogram over
// [0,1], normalized by H*W=262144. feats [64, 384] -> feats @ W^T + b -> relu.
// W: [128, 384], b: [128]. out: [64, 128] f32.

#define BINS 128
#define NSLICE 192               // B*C = 64*3
#define SLICE_ELEMS 262144       // 512*512
#define CHUNKS 16                // blocks per slice
#define CHUNK_ELEMS (SLICE_ELEMS / CHUNKS)   // 16384
#define THREADS 256
#define WAVES 4                  // THREADS/64

__global__ __launch_bounds__(THREADS) void hist_kernel(const float* __restrict__ x,
                                                       unsigned int* __restrict__ ghist) {
    __shared__ unsigned int lh[WAVES][BINS];

    const int bid   = blockIdx.x;
    const int slice = bid / CHUNKS;
    const int chunk = bid % CHUNKS;
    const int tid   = threadIdx.x;
    const int wave  = tid >> 6;

    // zero LDS histograms
    for (int i = tid; i < WAVES * BINS; i += THREADS)
        ((unsigned int*)lh)[i] = 0u;
    __syncthreads();

    // coalesced float4 walk over this chunk
    const float4* __restrict__ x4 = (const float4*)x;
    const int base4 = (slice * SLICE_ELEMS + chunk * CHUNK_ELEMS) >> 2;  // float4 units
    const int n4 = CHUNK_ELEMS >> 2;  // 4096 float4 per chunk
#pragma unroll 4
    for (int i = tid; i < n4; i += THREADS) {
        float4 v = x4[base4 + i];
        float vv[4] = {v.x, v.y, v.z, v.w};
#pragma unroll
        for (int j = 0; j < 4; ++j) {
            float f = vv[j];
            if (f >= 0.0f && f <= 1.0f) {
                int idx = (int)(f * (float)BINS);   // trunc == floor for f>=0
                if (idx > BINS - 1) idx = BINS - 1; // f == 1.0 -> last bin
                atomicAdd(&lh[wave][idx], 1u);
            }
        }
    }
    __syncthreads();

    // merge per-wave copies, one global atomic per bin per block
    if (tid < BINS) {
        unsigned int s = lh[0][tid] + lh[1][tid] + lh[2][tid] + lh[3][tid];
        atomicAdd(&ghist[slice * BINS + tid], s);
    }
}

__global__ __launch_bounds__(128) void gemm_kernel(const unsigned int* __restrict__ ghist,
                                                   const float* __restrict__ W,
                                                   const float* __restrict__ bias,
                                                   float* __restrict__ out) {
    const int b = blockIdx.x;   // 0..63
    const int n = threadIdx.x;  // 0..127

    __shared__ float h[3 * BINS];  // 384
    const float inv = 1.0f / (float)SLICE_ELEMS;
    for (int k = n; k < 3 * BINS; k += 128)
        h[k] = (float)ghist[b * 3 * BINS + k] * inv;
    __syncthreads();

    float acc = bias[n];
    const float4* __restrict__ Wr = (const float4*)(W + n * 3 * BINS);
#pragma unroll 8
    for (int k4 = 0; k4 < (3 * BINS) / 4; ++k4) {
        float4 w = Wr[k4];
        acc += w.x * h[k4 * 4 + 0] + w.y * h[k4 * 4 + 1] +
               w.z * h[k4 * 4 + 2] + w.w * h[k4 * 4 + 3];
    }
    out[b * 128 + n] = fmaxf(acc, 0.0f);
}

extern "C" void kernel_launch(void* const* d_in, const int* in_sizes, int n_in,
                              void* d_out, int out_size, void* d_ws, size_t ws_size,
                              hipStream_t stream) {
    const float* x    = (const float*)d_in[0];
    const float* W    = (const float*)d_in[1];
    const float* bias = (const float*)d_in[2];
    float* out        = (float*)d_out;
    unsigned int* ghist = (unsigned int*)d_ws;  // 192*128 uints = 96 KB

    hipMemsetAsync(ghist, 0, NSLICE * BINS * sizeof(unsigned int), stream);
    hist_kernel<<<NSLICE * CHUNKS, THREADS, 0, stream>>>(x, ghist);
    gemm_kernel<<<64, 128, 0, stream>>>(ghist, W, bias, out);
}

// Round 2
// 44.129 us; speedup vs baseline: 1.1086x; 1.1086x over previous
//
#include <hip/hip_runtime.h>

// x: [64, 3, 512, 512] f32 in [0,1). Per (b,c) slice: 128-bin histogram over
// [0,1] (torch.histc semantics), normalized by H*W=262144.
// feats [64, 384] -> feats @ W^T + b -> relu. W: [128, 384], b: [128].
// out: [64, 128] f32.
//
// Two dispatches, no memset:
//   1) hist_part: per-block (slice-chunk) partial histogram via per-wave LDS
//      atomics, plain-store 128 uints to d_ws (each block owns its slot ->
//      no zeroing across graph replays needed).
//   2) reduce_gemm: sum 16 partials per slice, normalize, dot with W, relu.

#define BINS 128
#define NSLICE 192               // B*C = 64*3
#define SLICE_ELEMS 262144       // 512*512
#define CHUNKS 16                // blocks per slice
#define CHUNK_ELEMS (SLICE_ELEMS / CHUNKS)   // 16384
#define THREADS 256
#define WAVES 4                  // THREADS/64

__global__ __launch_bounds__(THREADS) void hist_part(const float* __restrict__ x,
                                                     unsigned int* __restrict__ part) {
    __shared__ unsigned int lh[WAVES][BINS];

    const int bid  = blockIdx.x;           // slice*CHUNKS + chunk
    const int tid  = threadIdx.x;
    const int wave = tid >> 6;

    for (int i = tid; i < WAVES * BINS; i += THREADS)
        ((unsigned int*)lh)[i] = 0u;
    __syncthreads();

    const float4* __restrict__ x4 = (const float4*)x;
    const int base4 = bid * (CHUNK_ELEMS >> 2);
    const int n4 = CHUNK_ELEMS >> 2;  // 4096 float4 per chunk
#pragma unroll 4
    for (int i = tid; i < n4; i += THREADS) {
        float4 v = x4[base4 + i];
        float vv[4] = {v.x, v.y, v.z, v.w};
#pragma unroll
        for (int j = 0; j < 4; ++j) {
            float f = vv[j];
            if (f >= 0.0f && f <= 1.0f) {
                int idx = (int)(f * (float)BINS);   // trunc == floor for f>=0; exact pow2 mul
                if (idx > BINS - 1) idx = BINS - 1; // f == 1.0 -> last bin
                atomicAdd(&lh[wave][idx], 1u);
            }
        }
    }
    __syncthreads();

    if (tid < BINS) {
        unsigned int s = lh[0][tid] + lh[1][tid] + lh[2][tid] + lh[3][tid];
        part[bid * BINS + tid] = s;   // plain store: block owns this slot
    }
}

__global__ __launch_bounds__(128) void reduce_gemm(const unsigned int* __restrict__ part,
                                                   const float* __restrict__ W,
                                                   const float* __restrict__ bias,
                                                   float* __restrict__ out) {
    const int b = blockIdx.x;   // 0..63
    const int n = threadIdx.x;  // 0..127

    __shared__ float h[3 * BINS];  // 384
    const float inv = 1.0f / (float)SLICE_ELEMS;
    for (int k = n; k < 3 * BINS; k += 128) {
        const int slice = b * 3 + (k >> 7);
        const int bin   = k & (BINS - 1);
        const unsigned int* __restrict__ p = part + (size_t)slice * CHUNKS * BINS + bin;
        unsigned int s = 0;
#pragma unroll
        for (int c = 0; c < CHUNKS; ++c)
            s += p[c * BINS];      // lanes n consecutive -> coalesced
        h[k] = (float)s * inv;
    }
    __syncthreads();

    float acc = bias[n];
    const float4* __restrict__ Wr = (const float4*)(W + n * 3 * BINS);
#pragma unroll 8
    for (int k4 = 0; k4 < (3 * BINS) / 4; ++k4) {
        float4 w = Wr[k4];
        acc += w.x * h[k4 * 4 + 0] + w.y * h[k4 * 4 + 1] +
               w.z * h[k4 * 4 + 2] + w.w * h[k4 * 4 + 3];
    }
    out[b * 128 + n] = fmaxf(acc, 0.0f);
}

// ---- fallback path (ws too small): proven R1 kernels ----

__global__ __launch_bounds__(THREADS) void hist_atomic(const float* __restrict__ x,
                                                       unsigned int* __restrict__ ghist) {
    __shared__ unsigned int lh[WAVES][BINS];
    const int bid   = blockIdx.x;
    const int slice = bid / CHUNKS;
    const int tid   = threadIdx.x;
    const int wave  = tid >> 6;
    for (int i = tid; i < WAVES * BINS; i += THREADS)
        ((unsigned int*)lh)[i] = 0u;
    __syncthreads();
    const float4* __restrict__ x4 = (const float4*)x;
    const int base4 = bid * (CHUNK_ELEMS >> 2);
    const int n4 = CHUNK_ELEMS >> 2;
#pragma unroll 4
    for (int i = tid; i < n4; i += THREADS) {
        float4 v = x4[base4 + i];
        float vv[4] = {v.x, v.y, v.z, v.w};
#pragma unroll
        for (int j = 0; j < 4; ++j) {
            float f = vv[j];
            if (f >= 0.0f && f <= 1.0f) {
                int idx = (int)(f * (float)BINS);
                if (idx > BINS - 1) idx = BINS - 1;
                atomicAdd(&lh[wave][idx], 1u);
            }
        }
    }
    __syncthreads();
    if (tid < BINS) {
        unsigned int s = lh[0][tid] + lh[1][tid] + lh[2][tid] + lh[3][tid];
        atomicAdd(&ghist[slice * BINS + tid], s);
    }
}

__global__ __launch_bounds__(128) void gemm_atomic(const unsigned int* __restrict__ ghist,
                                                   const float* __restrict__ W,
                                                   const float* __restrict__ bias,
                                                   float* __restrict__ out) {
    const int b = blockIdx.x;
    const int n = threadIdx.x;
    __shared__ float h[3 * BINS];
    const float inv = 1.0f / (float)SLICE_ELEMS;
    for (int k = n; k < 3 * BINS; k += 128)
        h[k] = (float)ghist[b * 3 * BINS + k] * inv;
    __syncthreads();
    float acc = bias[n];
    const float4* __restrict__ Wr = (const float4*)(W + n * 3 * BINS);
#pragma unroll 8
    for (int k4 = 0; k4 < (3 * BINS) / 4; ++k4) {
        float4 w = Wr[k4];
        acc += w.x * h[k4 * 4 + 0] + w.y * h[k4 * 4 + 1] +
               w.z * h[k4 * 4 + 2] + w.w * h[k4 * 4 + 3];
    }
    out[b * 128 + n] = fmaxf(acc, 0.0f);
}

extern "C" void kernel_launch(void* const* d_in, const int* in_sizes, int n_in,
                              void* d_out, int out_size, void* d_ws, size_t ws_size,
                              hipStream_t stream) {
    const float* x    = (const float*)d_in[0];
    const float* W    = (const float*)d_in[1];
    const float* bias = (const float*)d_in[2];
    float* out        = (float*)d_out;

    const size_t need = (size_t)NSLICE * CHUNKS * BINS * sizeof(unsigned int); // 1.57 MB
    if (ws_size >= need) {
        unsigned int* part = (unsigned int*)d_ws;
        hist_part<<<NSLICE * CHUNKS, THREADS, 0, stream>>>(x, part);
        reduce_gemm<<<64, 128, 0, stream>>>(part, W, bias, out);
    } else {
        unsigned int* ghist = (unsigned int*)d_ws;  // 96 KB
        hipMemsetAsync(ghist, 0, NSLICE * BINS * sizeof(unsigned int), stream);
        hist_atomic<<<NSLICE * CHUNKS, THREADS, 0, stream>>>(x, ghist);
        gemm_atomic<<<64, 128, 0, stream>>>(ghist, W, bias, out);
    }
}